// Round 2
// baseline (8840.856 us; speedup 1.0000x reference)
//
#include <hip/hip_runtime.h>
#include <hip/hip_bf16.h>
#include <hip/hip_fp16.h>

// ---------------------------------------------------------------------------
// MGAN forward. f32 compute, fp16 storage for big intermediates.
//   B=256 S=128 A=8 L=32 D=H=300 NC=3 VOCAB=32000
// Workspace budget ~216 MB:
//   P (fp16, 167MB) overlaid later by ctx/ctxT/aspc (fp16, 81MB);
//   hseqC fp16 39.3MB; hseqA fp16 2.5MB; carry/cell f32; smalls f32.
// ---------------------------------------------------------------------------

#define NB   256
#define NS   128
#define NA   8
#define NL   32
#define ND   300
#define NH   300
#define NG4  1200
#define NPROJ 2400
#define TOK_CTX 32768
#define TOK_ALL 34816

typedef _Float16 h8 __attribute__((ext_vector_type(8)));

// ---------------- K0: sequence lengths ----------------
__global__ void k_lengths(const int* __restrict__ text, const int* __restrict__ aspect,
                          const int* __restrict__ left, int* __restrict__ lens) {
  int b = threadIdx.x;
  if (b >= NB) return;
  int ll = 0; for (int i = 0; i < NL; i++) ll += (left[b*NL + i] != 0);
  int cl = 0; for (int i = 0; i < NS; i++) cl += (text[b*NS + i] != 0);
  int al = 0; for (int i = 0; i < NA; i++) al += (aspect[b*NA + i] != 0);
  lens[b] = ll; lens[NB + b] = cl; lens[2*NB + b] = al;
}

// ---------------- K1: input projection GEMM (emb-gather fused) ----------------
// P[r][n] = sum_k emb[tok(r)][k] * W[n][k] + bias[n], r<34816, n<2400 (fp16 out)
__global__ __launch_bounds__(256) void k_inproj(
    const float* __restrict__ emb, const int* __restrict__ text, const int* __restrict__ aspect,
    const float* __restrict__ Wih_f, const float* __restrict__ Wih_b,
    const float* __restrict__ bih_f, const float* __restrict__ bhh_f,
    const float* __restrict__ bih_b, const float* __restrict__ bhh_b,
    _Float16* __restrict__ P)
{
  const int KC = 20;
  __shared__ __align__(16) float As[KC][132];
  __shared__ __align__(16) float Bs[KC][132];
  __shared__ int toks[128];
  const int m0 = blockIdx.x * 128;
  const int n0 = blockIdx.y * 128;
  const int tid = threadIdx.x;
  const int tx = tid & 15, ty = tid >> 4;
  float acc[8][8];
  #pragma unroll
  for (int i = 0; i < 8; i++)
    #pragma unroll
    for (int j = 0; j < 8; j++) acc[i][j] = 0.f;

  if (tid < 128) {
    int r = m0 + tid;
    toks[tid] = (r < TOK_CTX) ? text[r] : aspect[r - TOK_CTX];
  }
  __syncthreads();

  for (int kc = 0; kc < 300; kc += KC) {
    #pragma unroll
    for (int i = 0; i < 10; i++) {
      int u = tid + i*256;
      int mm = u / KC, kk = u - mm*KC;
      As[kk][mm] = emb[(long)toks[mm]*ND + kc + kk];
    }
    #pragma unroll
    for (int i = 0; i < 10; i++) {
      int u = tid + i*256;
      int nn = u / KC, kk = u - nn*KC;
      int n = n0 + nn;
      float v = 0.f;
      if (n < NPROJ) v = (n < NG4) ? Wih_f[n*ND + kc + kk] : Wih_b[(n - NG4)*ND + kc + kk];
      Bs[kk][nn] = v;
    }
    __syncthreads();
    #pragma unroll
    for (int k = 0; k < KC; k++) {
      float4 a0 = *(const float4*)&As[k][ty*8];
      float4 a1 = *(const float4*)&As[k][ty*8 + 4];
      float4 b0 = *(const float4*)&Bs[k][tx*8];
      float4 b1 = *(const float4*)&Bs[k][tx*8 + 4];
      float am[8] = {a0.x,a0.y,a0.z,a0.w,a1.x,a1.y,a1.z,a1.w};
      float bn[8] = {b0.x,b0.y,b0.z,b0.w,b1.x,b1.y,b1.z,b1.w};
      #pragma unroll
      for (int i = 0; i < 8; i++)
        #pragma unroll
        for (int j = 0; j < 8; j++) acc[i][j] += am[i]*bn[j];
    }
    __syncthreads();
  }
  int nbase = n0 + tx*8;
  if (nbase < NPROJ) {
    float bias[8];
    #pragma unroll
    for (int j = 0; j < 8; j++) {
      int nn = nbase + j;
      bias[j] = (nn < NG4) ? (bih_f[nn] + bhh_f[nn]) : (bih_b[nn - NG4] + bhh_b[nn - NG4]);
    }
    #pragma unroll
    for (int i = 0; i < 8; i++) {
      long r = m0 + ty*8 + i;
      h8 o;
      #pragma unroll
      for (int j = 0; j < 8; j++) o[j] = (_Float16)(acc[i][j] + bias[j]);
      *(h8*)&P[r*NPROJ + nbase] = o;
    }
  }
}

// ---------------- K2: one LSTM time step (both directions) ----------------
// grid (75,2,4): hg, dir, batch-group ; block 256 = 64 lanes(batch) x 4 waves(h)
__global__ __launch_bounds__(256) void k_lstm_step(
    const _Float16* __restrict__ P, const float* __restrict__ Whh_f, const float* __restrict__ Whh_b,
    const int* __restrict__ lenp,
    float* __restrict__ hcar,   // [2buf][2][256][300] f32
    float* __restrict__ cst,    // [2][300][256] f32
    _Float16* __restrict__ hseq, // [2][T][300][256] fp16
    int t, int T, int prow0)
{
  const int lane = threadIdx.x & 63;
  const int wv   = threadIdx.x >> 6;
  const int hg = blockIdx.x, d = blockIdx.y, mg = blockIdx.z;
  const int h  = __builtin_amdgcn_readfirstlane(hg*4 + wv);
  const int b  = mg*64 + lane;
  const float* __restrict__ Whh = d ? Whh_b : Whh_f;
  const float* __restrict__ W0 = Whh + (      h)*300;
  const float* __restrict__ W1 = Whh + (300 + h)*300;
  const float* __restrict__ W2 = Whh + (600 + h)*300;
  const float* __restrict__ W3 = Whh + (900 + h)*300;
  __shared__ __align__(16) float hs[64*128];   // [m][128] with XOR swizzle
  float acc[4] = {0.f, 0.f, 0.f, 0.f};
  float hp = 0.f;

  if (t > 0) {
    const float* __restrict__ hprev = hcar + ((long)((((t-1)&1))*2 + d)*256 + mg*64)*300;
    const int mm = threadIdx.x >> 2;
    const int kq = threadIdx.x & 3;
    const int wswz = (mm & 7) << 2;
    const int rswz = (lane & 7) << 2;
    for (int kc = 0; kc < 300; kc += 100) {
      __syncthreads();
      #pragma unroll
      for (int i = 0; i < 7; i++) {
        int kin = kq*4 + i*16;
        if (kin < 100) {
          float4 v = *(const float4*)&hprev[mm*300 + kc + kin];
          *(float4*)&hs[mm*128 + (kin ^ wswz)] = v;
        }
      }
      __syncthreads();
      #pragma unroll
      for (int q = 0; q < 25; q++) {
        int kk = q*4;
        float4 a = *(const float4*)&hs[lane*128 + (kk ^ rswz)];
        int kg = kc + kk;
        #pragma unroll
        for (int g = 0; g < 4; g++) {
          const float* Wg = (g==0) ? W0 : (g==1) ? W1 : (g==2) ? W2 : W3;
          acc[g] += a.x*Wg[kg] + a.y*Wg[kg+1] + a.z*Wg[kg+2] + a.w*Wg[kg+3];
        }
      }
      if (h >= kc && h < kc + 100) hp = hs[lane*128 + ((h - kc) ^ rswz)];
    }
  }

  const int len = lenp[b];
  int teff;
  if (d == 0) teff = t;
  else { int v = len - 1 - t; teff = v < 0 ? 0 : (v > T-1 ? T-1 : v); }
  const _Float16* __restrict__ Pr = P + (long)(prow0 + b*T + teff)*NPROJ + d*NG4 + h;
  float gi = acc[0] + (float)Pr[0];
  float gf = acc[1] + (float)Pr[300];
  float gg = acc[2] + (float)Pr[600];
  float go = acc[3] + (float)Pr[900];
  float cp = (t > 0) ? cst[(d*300 + h)*256 + b] : 0.f;
  float si = 1.f/(1.f + __expf(-gi));
  float sf = 1.f/(1.f + __expf(-gf));
  float so = 1.f/(1.f + __expf(-go));
  float cn = sf*cp + si*tanhf(gg);
  float hn = so*tanhf(cn);
  bool mt = t < len;
  float h2 = mt ? hn : hp;
  float c2 = mt ? cn : cp;
  cst[(d*300 + h)*256 + b] = c2;
  hcar[((long)((t&1)*2 + d)*256 + b)*300 + h] = h2;
  hseq[((long)(d*T + t)*300 + h)*256 + b] = (_Float16)(mt ? hn : 0.f);
}

// ---------------- K3: combine fwd/bwd + position weight -> ctx[b][s][600] ----------------
__global__ __launch_bounds__(256) void k_combine_ctx(
    const _Float16* __restrict__ hseq, const int* __restrict__ lens, _Float16* __restrict__ ctx)
{
  __shared__ float ldsv[150*65];
  const int s = blockIdx.x, bg = blockIdx.y, tid = threadIdx.x;
  const int lane = tid & 63, wvv = tid >> 6;
  for (int pass = 0; pass < 4; pass++) {
    int dir = pass >> 1, hc = (pass & 1)*150;
    __syncthreads();
    for (int u = tid; u < 150*64; u += 256) {
      int hh = u >> 6, bl = u & 63;
      int b = bg*64 + bl;
      float v;
      if (dir == 0) v = (float)hseq[((long)(0*NS + s)*300 + hc + hh)*256 + b];
      else {
        int cl = lens[NB + b];
        int tb0 = cl - 1 - s; int tb = tb0 < 0 ? 0 : (tb0 > NS-1 ? NS-1 : tb0);
        v = (s < cl) ? (float)hseq[((long)(NS + tb)*300 + hc + hh)*256 + b] : 0.f;
      }
      ldsv[hh*65 + bl] = v;
    }
    __syncthreads();
    for (int bi = 0; bi < 16; bi++) {
      int bl = wvv*16 + bi;
      int b = bg*64 + bl;
      float cl = (float)lens[NB + b], ll = (float)lens[b], al = (float)lens[2*NB + b];
      float tf = (float)s, denom = cl - al + 1.f;
      float wgt = (tf < ll) ? (1.f - (ll - tf)/denom)
                : (tf < ll + al) ? 0.f
                : (tf < cl) ? (1.f - (tf - ll - al + 1.f)/denom) : 0.f;
      #pragma unroll
      for (int i = 0; i < 3; i++) {
        int jj = lane + i*64;
        if (jj < 150) ctx[((long)b*NS + s)*600 + dir*300 + hc + jj] = (_Float16)(ldsv[jj*65 + bl] * wgt);
      }
    }
  }
}

// ---------------- K3b: transpose ctx -> ctxT[b][j][s] ----------------
__global__ void k_transpose(const _Float16* __restrict__ ctx, _Float16* __restrict__ ctxT) {
  __shared__ _Float16 tl[32][34];
  int b = blockIdx.x, s0 = blockIdx.y*32, j0 = blockIdx.z*32;
  int c = threadIdx.x & 31, r0 = threadIdx.x >> 5;
  #pragma unroll
  for (int i = 0; i < 4; i++) {
    int r = r0 + i*8;
    int j = j0 + c;
    tl[r][c] = (j < 600) ? ctx[((long)b*NS + s0 + r)*600 + j] : (_Float16)0.f;
  }
  __syncthreads();
  #pragma unroll
  for (int i = 0; i < 4; i++) {
    int r = r0 + i*8;
    int j = j0 + r;
    if (j < 600) ctxT[((long)b*600 + j)*NS + s0 + c] = tl[c][r];
  }
}

// ---------------- K4: aspect combine -> aspc[b][a][600] ----------------
__global__ void k_combine_asp(const _Float16* __restrict__ hseq, const int* __restrict__ lens,
                              _Float16* __restrict__ aspc) {
  int b = blockIdx.x, tid = threadIdx.x;
  int al = lens[2*NB + b];
  for (int a = 0; a < NA; a++) {
    for (int u = tid; u < 600; u += 512) {
      float v;
      if (u < 300) v = (float)hseq[((long)(0*NA + a)*300 + u)*256 + b];
      else {
        int tb0 = al - 1 - a; int tb = tb0 < 0 ? 0 : (tb0 > NA-1 ? NA-1 : tb0);
        v = (a < al) ? (float)hseq[((long)(NA + tb)*300 + (u - 300))*256 + b] : 0.f;
      }
      aspc[((long)b*NA + a)*600 + u] = (_Float16)v;
    }
  }
}

// ---------------- K5: c_avg, a_avg ----------------
__global__ void k_avg(const _Float16* __restrict__ ctx, const _Float16* __restrict__ aspc,
                      const int* __restrict__ lens, float* __restrict__ c_avg, float* __restrict__ a_avg) {
  int b = blockIdx.x, j = threadIdx.x;
  if (j >= 600) return;
  float ac = 0.f;
  for (int s = 0; s < NS; s++) ac += (float)ctx[((long)b*NS + s)*600 + j];
  c_avg[(long)b*600 + j] = ac / (float)lens[NB + b];
  float aa = 0.f;
  for (int a = 0; a < NA; a++) aa += (float)aspc[((long)b*NA + a)*600 + j];
  a_avg[(long)b*600 + j] = aa / (float)lens[2*NB + b];
}

// ---------------- K6: s1 = a_avg@w1 ; s2 = c_avg@w2 ----------------
__global__ void k_sw(const float* __restrict__ a_avg, const float* __restrict__ c_avg,
                     const float* __restrict__ w1, const float* __restrict__ w2,
                     float* __restrict__ s1, float* __restrict__ s2) {
  __shared__ float src[8][600];
  int bg = blockIdx.x * 8, which = blockIdx.y, tid = threadIdx.x;
  const float* sp = which ? c_avg : a_avg;
  const float* w  = which ? w2 : w1;
  float* outp     = which ? s2 : s1;
  for (int u = tid; u < 8*600; u += 640) {
    int q = u / 600, dd = u - q*600;
    src[q][dd] = sp[(long)(bg + q)*600 + dd];
  }
  __syncthreads();
  int j = tid;
  if (j >= 600) return;
  float acc[8] = {0,0,0,0,0,0,0,0};
  for (int dd = 0; dd < 600; dd++) {
    float wvv = w[dd*600 + j];
    #pragma unroll
    for (int q = 0; q < 8; q++) acc[q] += src[q][dd] * wvv;
  }
  #pragma unroll
  for (int q = 0; q < 8; q++) outp[(long)(bg + q)*600 + j] = acc[q];
}

// ---------------- K7: alpha1 + mca ----------------
__global__ __launch_bounds__(128) void k_att_ctx(const _Float16* __restrict__ ctxT,
    const _Float16* __restrict__ ctx, const float* __restrict__ s1, float* __restrict__ mca) {
  int b = blockIdx.x, tid = threadIdx.x;
  __shared__ float sv[600];
  __shared__ float red[128];
  __shared__ float mx, sm;
  for (int u = tid; u < 600; u += 128) sv[u] = s1[(long)b*600 + u];
  __syncthreads();
  float sc = 0.f;
  for (int dd = 0; dd < 600; dd++) sc += sv[dd] * (float)ctxT[((long)b*600 + dd)*NS + tid];
  red[tid] = sc; __syncthreads();
  if (tid == 0) { float m = -1e30f; for (int i = 0; i < 128; i++) m = fmaxf(m, red[i]); mx = m; }
  __syncthreads();
  float e = __expf(sc - mx);
  red[tid] = e; __syncthreads();
  if (tid == 0) { float s = 0.f; for (int i = 0; i < 128; i++) s += red[i]; sm = s; }
  __syncthreads();
  float alpha = e / sm;
  red[tid] = alpha; __syncthreads();
  for (int i = 0; i < 5; i++) {
    int j = tid + i*128;
    if (j < 600) {
      float acc = 0.f;
      for (int s2 = 0; s2 < NS; s2++) acc += red[s2] * (float)ctx[((long)b*NS + s2)*600 + j];
      mca[(long)b*600 + j] = acc;
    }
  }
}

// ---------------- K8: alpha2 + mcc ----------------
__global__ void k_att_asp(const _Float16* __restrict__ aspc, const float* __restrict__ s2,
                          float* __restrict__ mcc) {
  int b = blockIdx.x, tid = threadIdx.x, wvv = tid >> 6, lane = tid & 63;
  __shared__ float sv[600];
  __shared__ float sc8[8];
  for (int u = tid; u < 600; u += 512) sv[u] = s2[(long)b*600 + u];
  __syncthreads();
  float p = 0.f;
  for (int dd = lane; dd < 600; dd += 64) p += sv[dd] * (float)aspc[((long)b*NA + wvv)*600 + dd];
  #pragma unroll
  for (int off = 32; off; off >>= 1) p += __shfl_down(p, off);
  if (lane == 0) sc8[wvv] = p;
  __syncthreads();
  float m = -1e30f;
  #pragma unroll
  for (int a = 0; a < 8; a++) m = fmaxf(m, sc8[a]);
  float es[8]; float ssum = 0.f;
  #pragma unroll
  for (int a = 0; a < 8; a++) { es[a] = __expf(sc8[a] - m); ssum += es[a]; }
  float inv = 1.f / ssum;
  for (int i = 0; i < 2; i++) {
    int j = tid + i*512;
    if (j < 600) {
      float acc = 0.f;
      #pragma unroll
      for (int a = 0; a < 8; a++) acc += es[a]*inv * (float)aspc[((long)b*NA + a)*600 + j];
      mcc[(long)b*600 + j] = acc;
    }
  }
}

// ---------------- K9: u tensor -> mfa, mfc ----------------
__global__ __launch_bounds__(128) void k_u(const _Float16* __restrict__ ctxT, const _Float16* __restrict__ ctx,
    const _Float16* __restrict__ aspc, const float* __restrict__ fc1_w, const float* __restrict__ fc1_b,
    float* __restrict__ mfa, float* __restrict__ mfc) {
  int b = blockIdx.x, tid = threadIdx.x;   // tid == s
  __shared__ __align__(16) float aspl[4800];   // [d][a]
  __shared__ float ua8[8];
  __shared__ float red[128];
  __shared__ float qa8[8];
  __shared__ float mx1, sm1;
  __shared__ float pal[128][8];
  for (int u = tid; u < 4800; u += 128) {
    int a = u / 600, dd = u - a*600;
    aspl[dd*8 + a] = (float)aspc[((long)b*NA + a)*600 + dd];
  }
  __syncthreads();
  const float* wc = fc1_w;
  const float* wa = fc1_w + 600;
  const float* wm = fc1_w + 1200;
  {
    int wvv = tid >> 6, lane = tid & 63;
    for (int q = 0; q < 4; q++) {
      int a = wvv*4 + q;
      float p = 0.f;
      for (int dd = lane; dd < 600; dd += 64) p += wa[dd] * aspl[dd*8 + a];
      #pragma unroll
      for (int off = 32; off; off >>= 1) p += __shfl_down(p, off);
      if (lane == 0) ua8[a] = p;
    }
  }
  __syncthreads();
  float x8[8] = {0,0,0,0,0,0,0,0};
  float uc = 0.f;
  for (int dd = 0; dd < 600; dd++) {
    float cv = (float)ctxT[((long)b*600 + dd)*NS + tid];
    uc += cv * wc[dd];
    float cm = cv * wm[dd];
    float4 a03 = *(const float4*)&aspl[dd*8];
    float4 a47 = *(const float4*)&aspl[dd*8 + 4];
    x8[0] += cm*a03.x; x8[1] += cm*a03.y; x8[2] += cm*a03.z; x8[3] += cm*a03.w;
    x8[4] += cm*a47.x; x8[5] += cm*a47.y; x8[6] += cm*a47.z; x8[7] += cm*a47.w;
  }
  float fb = fc1_b[0];
  float u8v[8]; float umax = -1e30f;
  #pragma unroll
  for (int a = 0; a < 8; a++) { u8v[a] = uc + ua8[a] + x8[a] + fb; umax = fmaxf(umax, u8v[a]); }
  float pa[8]; float psum = 0.f;
  #pragma unroll
  for (int a = 0; a < 8; a++) { pa[a] = __expf(u8v[a] - umax); psum += pa[a]; }
  float pin = 1.f / psum;
  #pragma unroll
  for (int a = 0; a < 8; a++) pal[tid][a] = pa[a] * pin;
  red[tid] = umax;
  __syncthreads();
  if (tid == 0) { float m = -1e30f; for (int i = 0; i < 128; i++) m = fmaxf(m, red[i]); mx1 = m; }
  if (tid < 8) { float s = 0.f; for (int i = 0; i < 128; i++) s += pal[i][tid]; qa8[tid] = s * (1.f/128.f); }
  __syncthreads();
  float e = __expf(umax - mx1);
  red[tid] = e;
  __syncthreads();
  if (tid == 0) { float s = 0.f; for (int i = 0; i < 128; i++) s += red[i]; sm1 = s; }
  __syncthreads();
  float alpha = e / sm1;
  red[tid] = alpha;
  __syncthreads();
  for (int i = 0; i < 5; i++) {
    int j = tid + i*128;
    if (j < 600) {
      float am = 0.f;
      for (int s2 = 0; s2 < NS; s2++) am += red[s2] * (float)ctx[((long)b*NS + s2)*600 + j];
      float4 a03 = *(const float4*)&aspl[j*8];
      float4 a47 = *(const float4*)&aspl[j*8 + 4];
      mfa[(long)b*600 + j] = am;
      mfc[(long)b*600 + j] = qa8[0]*a03.x + qa8[1]*a03.y + qa8[2]*a03.z + qa8[3]*a03.w
                           + qa8[4]*a47.x + qa8[5]*a47.y + qa8[6]*a47.z + qa8[7]*a47.w;
    }
  }
}

// ---------------- K10: final FC + softmax ----------------
__global__ void k_final(const float* __restrict__ mca, const float* __restrict__ mcc,
                        const float* __restrict__ mfa, const float* __restrict__ mfc,
                        const float* __restrict__ fc2_w, const float* __restrict__ fc2_b,
                        float* __restrict__ out) {
  int b = blockIdx.x, tid = threadIdx.x, c = tid >> 6, lane = tid & 63;
  __shared__ float lg[3];
  float p = 0.f;
  for (int u = lane; u < 2400; u += 64) {
    int piece = u / 600;
    int jj = u - piece*600;
    const float* src = (piece == 0) ? mca : (piece == 1) ? mcc : (piece == 2) ? mfa : mfc;
    p += src[(long)b*600 + jj] * fc2_w[c*2400 + u];
  }
  #pragma unroll
  for (int off = 32; off; off >>= 1) p += __shfl_down(p, off);
  if (lane == 0) lg[c] = p + fc2_b[c];
  __syncthreads();
  if (tid == 0) {
    float m = fmaxf(lg[0], fmaxf(lg[1], lg[2]));
    float e0 = __expf(lg[0]-m), e1 = __expf(lg[1]-m), e2 = __expf(lg[2]-m);
    float s = e0 + e1 + e2;
    out[b*3 + 0] = e0/s; out[b*3 + 1] = e1/s; out[b*3 + 2] = e2/s;
  }
}

// ---------------- host ----------------
extern "C" void kernel_launch(void* const* d_in, const int* in_sizes, int n_in,
                              void* d_out, int out_size, void* d_ws, size_t ws_size,
                              hipStream_t stream)
{
  const int*   text    = (const int*)d_in[0];
  const int*   aspect  = (const int*)d_in[1];
  const int*   left    = (const int*)d_in[2];
  const float* emb     = (const float*)d_in[3];
  const float* Wih_f   = (const float*)d_in[4];
  const float* Whh_f   = (const float*)d_in[5];
  const float* bih_f   = (const float*)d_in[6];
  const float* bhh_f   = (const float*)d_in[7];
  const float* Wih_b   = (const float*)d_in[8];
  const float* Whh_b   = (const float*)d_in[9];
  const float* bih_b   = (const float*)d_in[10];
  const float* bhh_b   = (const float*)d_in[11];
  const float* w1      = (const float*)d_in[12];
  const float* w2      = (const float*)d_in[13];
  const float* fc1_w   = (const float*)d_in[14];
  const float* fc1_b   = (const float*)d_in[15];
  const float* fc2_w   = (const float*)d_in[16];
  const float* fc2_b   = (const float*)d_in[17];
  float* out = (float*)d_out;

  // ---- workspace layout (bytes, 256-B aligned blocks) ----
  char* base = (char*)d_ws;
  size_t off = 0;
  auto alloc = [&](size_t bytes) -> void* {
    void* p = base + off;
    off = (off + bytes + 255) & ~(size_t)255;
    return p;
  };
  int*      lens  = (int*)     alloc(3 * NB * sizeof(int));
  float*    hcar  = (float*)   alloc((size_t)2*2*NB*NH * sizeof(float));      // 1.23 MB
  float*    cst   = (float*)   alloc((size_t)2*NH*NB * sizeof(float));        // 0.61 MB
  float*    c_avg = (float*)   alloc((size_t)NB*600 * sizeof(float));
  float*    a_avg = (float*)   alloc((size_t)NB*600 * sizeof(float));
  float*    s1    = (float*)   alloc((size_t)NB*600 * sizeof(float));
  float*    s2    = (float*)   alloc((size_t)NB*600 * sizeof(float));
  float*    mca   = (float*)   alloc((size_t)NB*600 * sizeof(float));
  float*    mcc   = (float*)   alloc((size_t)NB*600 * sizeof(float));
  float*    mfa   = (float*)   alloc((size_t)NB*600 * sizeof(float));
  float*    mfc   = (float*)   alloc((size_t)NB*600 * sizeof(float));
  _Float16* hseqC = (_Float16*)alloc((size_t)2*NS*NH*NB * sizeof(_Float16));  // 39.3 MB
  _Float16* hseqA = (_Float16*)alloc((size_t)2*NA*NH*NB * sizeof(_Float16));  // 2.46 MB
  // BIG overlay region: P (167.1 MB) first, later reused for ctx/ctxT/aspc (81.1 MB)
  size_t bigBytes = (size_t)TOK_ALL * NPROJ * sizeof(_Float16);
  char*  bigBase  = (char*)alloc(bigBytes);
  _Float16* P     = (_Float16*)bigBase;
  _Float16* ctx   = (_Float16*)bigBase;                                        // overlay (P dead)
  _Float16* ctxT  = ctx  + (size_t)NB*NS*600;
  _Float16* aspc  = ctxT + (size_t)NB*NS*600;
  size_t need = off;
  if (ws_size < need) return;  // clean zero-output signal instead of OOB

  k_lengths<<<1, 256, 0, stream>>>(text, aspect, left, lens);
  k_inproj<<<dim3(272, 19), 256, 0, stream>>>(emb, text, aspect, Wih_f, Wih_b,
                                              bih_f, bhh_f, bih_b, bhh_b, P);
  for (int t = 0; t < NS; t++)
    k_lstm_step<<<dim3(75, 2, 4), 256, 0, stream>>>(P, Whh_f, Whh_b, lens + NB,
                                                    hcar, cst, hseqC, t, NS, 0);
  for (int t = 0; t < NA; t++)
    k_lstm_step<<<dim3(75, 2, 4), 256, 0, stream>>>(P, Whh_f, Whh_b, lens + 2*NB,
                                                    hcar, cst, hseqA, t, NA, TOK_CTX);
  k_combine_ctx<<<dim3(128, 4), 256, 0, stream>>>(hseqC, lens, ctx);
  k_transpose<<<dim3(256, 4, 19), 256, 0, stream>>>(ctx, ctxT);
  k_combine_asp<<<256, 512, 0, stream>>>(hseqA, lens, aspc);
  k_avg<<<256, 640, 0, stream>>>(ctx, aspc, lens, c_avg, a_avg);
  k_sw<<<dim3(32, 2), 640, 0, stream>>>(a_avg, c_avg, w1, w2, s1, s2);
  k_att_ctx<<<256, 128, 0, stream>>>(ctxT, ctx, s1, mca);
  k_att_asp<<<256, 512, 0, stream>>>(aspc, s2, mcc);
  k_u<<<256, 128, 0, stream>>>(ctxT, ctx, aspc, fc1_w, fc1_b, mfa, mfc);
  k_final<<<256, 192, 0, stream>>>(mca, mcc, mfa, mfc, fc2_w, fc2_b, out);
}

// Round 3
// 2187.229 us; speedup vs baseline: 4.0420x; 4.0420x over previous
//
#include <hip/hip_runtime.h>
#include <hip/hip_bf16.h>
#include <hip/hip_fp16.h>

// ---------------------------------------------------------------------------
// MGAN forward. fp16 MFMA for input projection + recurrent matvec, f32 accum.
//   B=256 S=128 A=8 L=32 D=H=300 NC=3 VOCAB=32000
// MFMA 16x16x32_f16 fragment scheme (m89/m91-verified):
//   A-frag: lane holds A[m = l&15][k = (l>>4)*8 + j]
//   B-frag (B^T stored [n][k]): lane holds B[n = l&15][k = (l>>4)*8 + j]
//   D:      lane,reg r -> D[m = (l>>4)*4 + r][n = l&15]
// Weights stored padded: [dir][gate][304 rows][320 k] fp16 (zero pad) so
// 16-wide n-tiles never cross gate boundaries; K padded 300->320.
// ---------------------------------------------------------------------------

#define NB   256
#define NS   128
#define NA   8
#define NL   32
#define ND   300
#define NH   300
#define NPROJ 2400
#define NPAD  2432      // 2*4*304
#define KP    320
#define TOK_CTX 32768
#define TOK_ALL 34816

typedef _Float16 half8 __attribute__((ext_vector_type(8)));
typedef float    f32x4 __attribute__((ext_vector_type(4)));

// ---------------- K0: sequence lengths ----------------
__global__ void k_lengths(const int* __restrict__ text, const int* __restrict__ aspect,
                          const int* __restrict__ left, int* __restrict__ lens) {
  int b = threadIdx.x;
  if (b >= NB) return;
  int ll = 0; for (int i = 0; i < NL; i++) ll += (left[b*NL + i] != 0);
  int cl = 0; for (int i = 0; i < NS; i++) cl += (text[b*NS + i] != 0);
  int al = 0; for (int i = 0; i < NA; i++) al += (aspect[b*NA + i] != 0);
  lens[b] = ll; lens[NB + b] = cl; lens[2*NB + b] = al;
}

// ---------------- converters ----------------
__global__ void k_cvt_emb(const float* __restrict__ emb, _Float16* __restrict__ emb16) {
  const long N = (long)32000 * KP;
  for (long i = (long)blockIdx.x*blockDim.x + threadIdx.x; i < N; i += (long)gridDim.x*blockDim.x) {
    long v = i / KP; int k = (int)(i - v*KP);
    emb16[i] = (k < ND) ? (_Float16)emb[v*ND + k] : (_Float16)0.f;
  }
}

// y==0: Wih16, y==1: Whh16, y==2: bias_sum
__global__ void k_cvt_w(const float* __restrict__ Wih_f, const float* __restrict__ Wih_b,
                        const float* __restrict__ Whh_f, const float* __restrict__ Whh_b,
                        const float* __restrict__ bih_f, const float* __restrict__ bhh_f,
                        const float* __restrict__ bih_b, const float* __restrict__ bhh_b,
                        _Float16* __restrict__ Wih16, _Float16* __restrict__ Whh16,
                        float* __restrict__ bias_sum) {
  int y = blockIdx.y;
  if (y < 2) {
    const long N = (long)NPAD * KP;
    const float* sf = y ? Whh_f : Wih_f;
    const float* sb = y ? Whh_b : Wih_b;
    _Float16* dst = y ? Whh16 : Wih16;
    for (long i = (long)blockIdx.x*blockDim.x + threadIdx.x; i < N; i += (long)gridDim.x*blockDim.x) {
      long row = i / KP; int k = (int)(i - row*KP);
      int d = (int)(row / 1216); int rem = (int)(row - (long)d*1216);
      int g = rem / 304; int jj = rem - g*304;
      float v = 0.f;
      if (jj < NH && k < NH) {
        const float* src = d ? sb : sf;
        v = src[(long)(g*NH + jj)*NH + k];
      }
      dst[i] = (_Float16)v;
    }
  } else {
    for (int i = blockIdx.x*blockDim.x + threadIdx.x; i < NPAD; i += gridDim.x*blockDim.x) {
      int d = i / 1216; int rem = i - d*1216;
      int g = rem / 304; int jj = rem - g*304;
      float v = 0.f;
      if (jj < NH) {
        v = d ? (bih_b[g*NH + jj] + bhh_b[g*NH + jj]) : (bih_f[g*NH + jj] + bhh_f[g*NH + jj]);
      }
      bias_sum[i] = v;
    }
  }
}

// ---------------- K1: input projection GEMM via MFMA ----------------
// P[r][2400] = emb16[tok(r)][:] @ Wih16^T + bias. grid (272 m, 19 n), 256 thr.
__global__ __launch_bounds__(256) void k_inproj(
    const _Float16* __restrict__ emb16, const int* __restrict__ text, const int* __restrict__ aspect,
    const _Float16* __restrict__ Wih16, const float* __restrict__ bias_sum,
    _Float16* __restrict__ P)
{
  const int l = threadIdx.x & 63, w = threadIdx.x >> 6;
  const int m0 = blockIdx.x * 128, n0 = blockIdx.y * 128;
  const int lrow = l & 15, lk = (l >> 4) * 8;

  // token rows for this wave's 2 m-tiles
  const _Float16* ap[2];
  #pragma unroll
  for (int q = 0; q < 2; q++) {
    int r = m0 + (2*w + q)*16 + lrow;
    int tok = (r < TOK_CTX) ? text[r] : aspect[r - TOK_CTX];
    ap[q] = emb16 + (long)tok*KP + lk;
  }
  const _Float16* bp[8];
  #pragma unroll
  for (int nt = 0; nt < 8; nt++)
    bp[nt] = Wih16 + (long)(n0 + nt*16 + lrow)*KP + lk;

  f32x4 acc[2][8];
  #pragma unroll
  for (int q = 0; q < 2; q++)
    #pragma unroll
    for (int nt = 0; nt < 8; nt++) acc[q][nt] = (f32x4){0.f,0.f,0.f,0.f};

  #pragma unroll
  for (int k0 = 0; k0 < 10; k0++) {
    half8 a0 = *(const half8*)(ap[0] + k0*32);
    half8 a1 = *(const half8*)(ap[1] + k0*32);
    #pragma unroll
    for (int nt = 0; nt < 8; nt++) {
      half8 bb = *(const half8*)(bp[nt] + k0*32);
      acc[0][nt] = __builtin_amdgcn_mfma_f32_16x16x32_f16(a0, bb, acc[0][nt], 0, 0, 0);
      acc[1][nt] = __builtin_amdgcn_mfma_f32_16x16x32_f16(a1, bb, acc[1][nt], 0, 0, 0);
    }
  }

  #pragma unroll
  for (int nt = 0; nt < 8; nt++) {
    int ncol = n0 + nt*16 + lrow;
    int d = ncol / 1216; int rem = ncol - d*1216;
    int g = rem / 304;   int jj = rem - g*304;
    if (jj < NH) {
      float bias = bias_sum[ncol];
      long coff = (long)d*1200 + g*NH + jj;
      #pragma unroll
      for (int q = 0; q < 2; q++)
        #pragma unroll
        for (int r = 0; r < 4; r++) {
          long row = m0 + (2*w + q)*16 + (l>>4)*4 + r;
          P[row*NPROJ + coff] = (_Float16)(acc[q][nt][r] + bias);
        }
    }
  }
}

// ---------------- K2: one LSTM time step (both dirs) via MFMA ----------------
// grid (19 js, 2 d, 4 bg), 256 thr = 4 waves; wave w -> 16 batches.
__global__ __launch_bounds__(256) void k_lstm_step(
    const _Float16* __restrict__ P, const _Float16* __restrict__ Whh16,
    const int* __restrict__ lenp,
    _Float16* __restrict__ hcar,   // [2buf][2][256][320]
    float* __restrict__ cst,       // [2][256][300]
    _Float16* __restrict__ hseq,   // [2][T][256][300]
    int t, int T, int prow0)
{
  const int l = threadIdx.x & 63, w = threadIdx.x >> 6;
  const int js = blockIdx.x, d = blockIdx.y, b0 = blockIdx.z * 64;
  const int lrow = l & 15, lk = (l >> 4) * 8;

  const _Float16* rbuf = hcar + ((size_t)((t & 1)*2 + d)*256)*KP;
  _Float16*       wbuf = hcar + ((size_t)((((t+1) & 1))*2 + d)*256)*KP;

  const _Float16* ap = rbuf + (size_t)(b0 + w*16 + lrow)*KP + lk;
  const _Float16* bp[4];
  #pragma unroll
  for (int g = 0; g < 4; g++)
    bp[g] = Whh16 + ((size_t)(d*4 + g)*304 + js*16 + lrow)*KP + lk;

  f32x4 acc[4];
  #pragma unroll
  for (int g = 0; g < 4; g++) acc[g] = (f32x4){0.f,0.f,0.f,0.f};

  #pragma unroll
  for (int k0 = 0; k0 < 10; k0++) {
    half8 a = *(const half8*)(ap + k0*32);
    #pragma unroll
    for (int g = 0; g < 4; g++) {
      half8 bb = *(const half8*)(bp[g] + k0*32);
      acc[g] = __builtin_amdgcn_mfma_f32_16x16x32_f16(a, bb, acc[g], 0, 0, 0);
    }
  }

  const int j = js*16 + lrow;
  const bool jv = (j < NH);
  #pragma unroll
  for (int r = 0; r < 4; r++) {
    int b = b0 + w*16 + (l >> 4)*4 + r;
    int len = lenp[b];
    int teff;
    if (d == 0) teff = t;
    else { int v = len - 1 - t; teff = v < 0 ? 0 : (v > T-1 ? T-1 : v); }
    const _Float16* Pr = P + ((size_t)(prow0 + b*T + teff))*NPROJ + d*1200;
    float gi = acc[0][r], gf = acc[1][r], gg = acc[2][r], go = acc[3][r];
    float cp = 0.f, hp = 0.f;
    if (jv) {
      gi += (float)Pr[      j];
      gf += (float)Pr[NH  + j];
      gg += (float)Pr[2*NH+ j];
      go += (float)Pr[3*NH+ j];
      cp = cst[((size_t)d*256 + b)*NH + j];
      hp = (float)rbuf[(size_t)b*KP + j];
    }
    float si = 1.f/(1.f + __expf(-gi));
    float sf = 1.f/(1.f + __expf(-gf));
    float so = 1.f/(1.f + __expf(-go));
    float cn = sf*cp + si*tanhf(gg);
    float hn = so*tanhf(cn);
    bool mt = t < len;
    float h2 = mt ? hn : hp;
    float c2 = mt ? cn : cp;
    if (jv) {
      cst[((size_t)d*256 + b)*NH + j] = c2;
      wbuf[(size_t)b*KP + j] = (_Float16)h2;
      hseq[(((size_t)d*T + t)*256 + b)*NH + j] = (_Float16)(mt ? hn : 0.f);
    }
  }
}

// ---------------- K3: combine + position weight -> ctx[b][s][600] ----------------
__global__ __launch_bounds__(320) void k_combine_ctx(
    const _Float16* __restrict__ hseq, const int* __restrict__ lens, _Float16* __restrict__ ctx)
{
  const int s = blockIdx.x, bg = blockIdx.y, tid = threadIdx.x;
  if (tid >= NH) return;
  for (int bq = 0; bq < 16; bq++) {
    int b = bg*16 + bq;
    int cl = lens[NB + b], ll = lens[b], al = lens[2*NB + b];
    float clf = (float)cl, llf = (float)ll, alf = (float)al;
    float tf = (float)s, denom = clf - alf + 1.f;
    float wgt = (tf < llf) ? (1.f - (llf - tf)/denom)
              : (tf < llf + alf) ? 0.f
              : (tf < clf) ? (1.f - (tf - llf - alf + 1.f)/denom) : 0.f;
    float vf = (float)hseq[((size_t)s*256 + b)*NH + tid];
    int tb0 = cl - 1 - s; int tb = tb0 < 0 ? 0 : (tb0 > NS-1 ? NS-1 : tb0);
    float vb = (s < cl) ? (float)hseq[((size_t)(NS + tb)*256 + b)*NH + tid] : 0.f;
    ctx[((size_t)b*NS + s)*600 + tid]      = (_Float16)(vf * wgt);
    ctx[((size_t)b*NS + s)*600 + NH + tid] = (_Float16)(vb * wgt);
  }
}

// ---------------- K3b: transpose ctx -> ctxT[b][j][s] ----------------
__global__ void k_transpose(const _Float16* __restrict__ ctx, _Float16* __restrict__ ctxT) {
  __shared__ _Float16 tl[32][34];
  int b = blockIdx.x, s0 = blockIdx.y*32, j0 = blockIdx.z*32;
  int c = threadIdx.x & 31, r0 = threadIdx.x >> 5;
  #pragma unroll
  for (int i = 0; i < 4; i++) {
    int r = r0 + i*8;
    int j = j0 + c;
    tl[r][c] = (j < 600) ? ctx[((long)b*NS + s0 + r)*600 + j] : (_Float16)0.f;
  }
  __syncthreads();
  #pragma unroll
  for (int i = 0; i < 4; i++) {
    int r = r0 + i*8;
    int j = j0 + r;
    if (j < 600) ctxT[((long)b*600 + j)*NS + s0 + c] = tl[c][r];
  }
}

// ---------------- K4: aspect combine -> aspc[b][a][600] ----------------
__global__ __launch_bounds__(320) void k_combine_asp(
    const _Float16* __restrict__ hseq, const int* __restrict__ lens, _Float16* __restrict__ aspc)
{
  int b = blockIdx.x, tid = threadIdx.x;
  if (tid >= NH) return;
  int al = lens[2*NB + b];
  for (int a = 0; a < NA; a++) {
    float vf = (float)hseq[((size_t)a*256 + b)*NH + tid];
    int tb0 = al - 1 - a; int tb = tb0 < 0 ? 0 : (tb0 > NA-1 ? NA-1 : tb0);
    float vb = (a < al) ? (float)hseq[((size_t)(NA + tb)*256 + b)*NH + tid] : 0.f;
    aspc[((size_t)b*NA + a)*600 + tid]      = (_Float16)vf;
    aspc[((size_t)b*NA + a)*600 + NH + tid] = (_Float16)vb;
  }
}

// ---------------- K5: c_avg, a_avg ----------------
__global__ void k_avg(const _Float16* __restrict__ ctx, const _Float16* __restrict__ aspc,
                      const int* __restrict__ lens, float* __restrict__ c_avg, float* __restrict__ a_avg) {
  int b = blockIdx.x, j = threadIdx.x;
  if (j >= 600) return;
  float ac = 0.f;
  for (int s = 0; s < NS; s++) ac += (float)ctx[((long)b*NS + s)*600 + j];
  c_avg[(long)b*600 + j] = ac / (float)lens[NB + b];
  float aa = 0.f;
  for (int a = 0; a < NA; a++) aa += (float)aspc[((long)b*NA + a)*600 + j];
  a_avg[(long)b*600 + j] = aa / (float)lens[2*NB + b];
}

// ---------------- K6: s1 = a_avg@w1 ; s2 = c_avg@w2 ----------------
__global__ void k_sw(const float* __restrict__ a_avg, const float* __restrict__ c_avg,
                     const float* __restrict__ w1, const float* __restrict__ w2,
                     float* __restrict__ s1, float* __restrict__ s2) {
  __shared__ float src[8][600];
  int bg = blockIdx.x * 8, which = blockIdx.y, tid = threadIdx.x;
  const float* sp = which ? c_avg : a_avg;
  const float* w  = which ? w2 : w1;
  float* outp     = which ? s2 : s1;
  for (int u = tid; u < 8*600; u += 640) {
    int q = u / 600, dd = u - q*600;
    src[q][dd] = sp[(long)(bg + q)*600 + dd];
  }
  __syncthreads();
  int j = tid;
  if (j >= 600) return;
  float acc[8] = {0,0,0,0,0,0,0,0};
  for (int dd = 0; dd < 600; dd++) {
    float wvv = w[dd*600 + j];
    #pragma unroll
    for (int q = 0; q < 8; q++) acc[q] += src[q][dd] * wvv;
  }
  #pragma unroll
  for (int q = 0; q < 8; q++) outp[(long)(bg + q)*600 + j] = acc[q];
}

// ---------------- K7: alpha1 + mca ----------------
__global__ __launch_bounds__(128) void k_att_ctx(const _Float16* __restrict__ ctxT,
    const _Float16* __restrict__ ctx, const float* __restrict__ s1, float* __restrict__ mca) {
  int b = blockIdx.x, tid = threadIdx.x;
  __shared__ float sv[600];
  __shared__ float red[128];
  __shared__ float mx, sm;
  for (int u = tid; u < 600; u += 128) sv[u] = s1[(long)b*600 + u];
  __syncthreads();
  float sc = 0.f;
  for (int dd = 0; dd < 600; dd++) sc += sv[dd] * (float)ctxT[((long)b*600 + dd)*NS + tid];
  red[tid] = sc; __syncthreads();
  if (tid == 0) { float m = -1e30f; for (int i = 0; i < 128; i++) m = fmaxf(m, red[i]); mx = m; }
  __syncthreads();
  float e = __expf(sc - mx);
  red[tid] = e; __syncthreads();
  if (tid == 0) { float s = 0.f; for (int i = 0; i < 128; i++) s += red[i]; sm = s; }
  __syncthreads();
  float alpha = e / sm;
  red[tid] = alpha; __syncthreads();
  for (int i = 0; i < 5; i++) {
    int j = tid + i*128;
    if (j < 600) {
      float acc = 0.f;
      for (int s2 = 0; s2 < NS; s2++) acc += red[s2] * (float)ctx[((long)b*NS + s2)*600 + j];
      mca[(long)b*600 + j] = acc;
    }
  }
}

// ---------------- K8: alpha2 + mcc ----------------
__global__ void k_att_asp(const _Float16* __restrict__ aspc, const float* __restrict__ s2,
                          float* __restrict__ mcc) {
  int b = blockIdx.x, tid = threadIdx.x, wvv = tid >> 6, lane = tid & 63;
  __shared__ float sv[600];
  __shared__ float sc8[8];
  for (int u = tid; u < 600; u += 512) sv[u] = s2[(long)b*600 + u];
  __syncthreads();
  float p = 0.f;
  for (int dd = lane; dd < 600; dd += 64) p += sv[dd] * (float)aspc[((long)b*NA + wvv)*600 + dd];
  #pragma unroll
  for (int off = 32; off; off >>= 1) p += __shfl_down(p, off);
  if (lane == 0) sc8[wvv] = p;
  __syncthreads();
  float m = -1e30f;
  #pragma unroll
  for (int a = 0; a < 8; a++) m = fmaxf(m, sc8[a]);
  float es[8]; float ssum = 0.f;
  #pragma unroll
  for (int a = 0; a < 8; a++) { es[a] = __expf(sc8[a] - m); ssum += es[a]; }
  float inv = 1.f / ssum;
  for (int i = 0; i < 2; i++) {
    int j = tid + i*512;
    if (j < 600) {
      float acc = 0.f;
      #pragma unroll
      for (int a = 0; a < 8; a++) acc += es[a]*inv * (float)aspc[((long)b*NA + a)*600 + j];
      mcc[(long)b*600 + j] = acc;
    }
  }
}

// ---------------- K9: u tensor -> mfa, mfc ----------------
__global__ __launch_bounds__(128) void k_u(const _Float16* __restrict__ ctxT, const _Float16* __restrict__ ctx,
    const _Float16* __restrict__ aspc, const float* __restrict__ fc1_w, const float* __restrict__ fc1_b,
    float* __restrict__ mfa, float* __restrict__ mfc) {
  int b = blockIdx.x, tid = threadIdx.x;   // tid == s
  __shared__ __align__(16) float aspl[4800];   // [d][a]
  __shared__ float ua8[8];
  __shared__ float red[128];
  __shared__ float qa8[8];
  __shared__ float mx1, sm1;
  __shared__ float pal[128][8];
  for (int u = tid; u < 4800; u += 128) {
    int a = u / 600, dd = u - a*600;
    aspl[dd*8 + a] = (float)aspc[((long)b*NA + a)*600 + dd];
  }
  __syncthreads();
  const float* wc = fc1_w;
  const float* wa = fc1_w + 600;
  const float* wm = fc1_w + 1200;
  {
    int wvv = tid >> 6, lane = tid & 63;
    for (int q = 0; q < 4; q++) {
      int a = wvv*4 + q;
      float p = 0.f;
      for (int dd = lane; dd < 600; dd += 64) p += wa[dd] * aspl[dd*8 + a];
      #pragma unroll
      for (int off = 32; off; off >>= 1) p += __shfl_down(p, off);
      if (lane == 0) ua8[a] = p;
    }
  }
  __syncthreads();
  float x8[8] = {0,0,0,0,0,0,0,0};
  float uc = 0.f;
  for (int dd = 0; dd < 600; dd++) {
    float cv = (float)ctxT[((long)b*600 + dd)*NS + tid];
    uc += cv * wc[dd];
    float cm = cv * wm[dd];
    float4 a03 = *(const float4*)&aspl[dd*8];
    float4 a47 = *(const float4*)&aspl[dd*8 + 4];
    x8[0] += cm*a03.x; x8[1] += cm*a03.y; x8[2] += cm*a03.z; x8[3] += cm*a03.w;
    x8[4] += cm*a47.x; x8[5] += cm*a47.y; x8[6] += cm*a47.z; x8[7] += cm*a47.w;
  }
  float fb = fc1_b[0];
  float u8v[8]; float umax = -1e30f;
  #pragma unroll
  for (int a = 0; a < 8; a++) { u8v[a] = uc + ua8[a] + x8[a] + fb; umax = fmaxf(umax, u8v[a]); }
  float pa[8]; float psum = 0.f;
  #pragma unroll
  for (int a = 0; a < 8; a++) { pa[a] = __expf(u8v[a] - umax); psum += pa[a]; }
  float pin = 1.f / psum;
  #pragma unroll
  for (int a = 0; a < 8; a++) pal[tid][a] = pa[a] * pin;
  red[tid] = umax;
  __syncthreads();
  if (tid == 0) { float m = -1e30f; for (int i = 0; i < 128; i++) m = fmaxf(m, red[i]); mx1 = m; }
  if (tid < 8) { float s = 0.f; for (int i = 0; i < 128; i++) s += pal[i][tid]; qa8[tid] = s * (1.f/128.f); }
  __syncthreads();
  float e = __expf(umax - mx1);
  red[tid] = e;
  __syncthreads();
  if (tid == 0) { float s = 0.f; for (int i = 0; i < 128; i++) s += red[i]; sm1 = s; }
  __syncthreads();
  float alpha = e / sm1;
  red[tid] = alpha;
  __syncthreads();
  for (int i = 0; i < 5; i++) {
    int j = tid + i*128;
    if (j < 600) {
      float am = 0.f;
      for (int s2 = 0; s2 < NS; s2++) am += red[s2] * (float)ctx[((long)b*NS + s2)*600 + j];
      float4 a03 = *(const float4*)&aspl[j*8];
      float4 a47 = *(const float4*)&aspl[j*8 + 4];
      mfa[(long)b*600 + j] = am;
      mfc[(long)b*600 + j] = qa8[0]*a03.x + qa8[1]*a03.y + qa8[2]*a03.z + qa8[3]*a03.w
                           + qa8[4]*a47.x + qa8[5]*a47.y + qa8[6]*a47.z + qa8[7]*a47.w;
    }
  }
}

// ---------------- K10: final FC + softmax ----------------
__global__ void k_final(const float* __restrict__ mca, const float* __restrict__ mcc,
                        const float* __restrict__ mfa, const float* __restrict__ mfc,
                        const float* __restrict__ fc2_w, const float* __restrict__ fc2_b,
                        float* __restrict__ out) {
  int b = blockIdx.x, tid = threadIdx.x, c = tid >> 6, lane = tid & 63;
  __shared__ float lg[3];
  float p = 0.f;
  for (int u = lane; u < 2400; u += 64) {
    int piece = u / 600;
    int jj = u - piece*600;
    const float* src = (piece == 0) ? mca : (piece == 1) ? mcc : (piece == 2) ? mfa : mfc;
    p += src[(long)b*600 + jj] * fc2_w[c*2400 + u];
  }
  #pragma unroll
  for (int off = 32; off; off >>= 1) p += __shfl_down(p, off);
  if (lane == 0) lg[c] = p + fc2_b[c];
  __syncthreads();
  if (tid == 0) {
    float m = fmaxf(lg[0], fmaxf(lg[1], lg[2]));
    float e0 = __expf(lg[0]-m), e1 = __expf(lg[1]-m), e2 = __expf(lg[2]-m);
    float s = e0 + e1 + e2;
    out[b*3 + 0] = e0/s; out[b*3 + 1] = e1/s; out[b*3 + 2] = e2/s;
  }
}

// ---------------- host ----------------
extern "C" void kernel_launch(void* const* d_in, const int* in_sizes, int n_in,
                              void* d_out, int out_size, void* d_ws, size_t ws_size,
                              hipStream_t stream)
{
  const int*   text    = (const int*)d_in[0];
  const int*   aspect  = (const int*)d_in[1];
  const int*   left    = (const int*)d_in[2];
  const float* emb     = (const float*)d_in[3];
  const float* Wih_f   = (const float*)d_in[4];
  const float* Whh_f   = (const float*)d_in[5];
  const float* bih_f   = (const float*)d_in[6];
  const float* bhh_f   = (const float*)d_in[7];
  const float* Wih_b   = (const float*)d_in[8];
  const float* Whh_b   = (const float*)d_in[9];
  const float* bih_b   = (const float*)d_in[10];
  const float* bhh_b   = (const float*)d_in[11];
  const float* w1      = (const float*)d_in[12];
  const float* w2      = (const float*)d_in[13];
  const float* fc1_w   = (const float*)d_in[14];
  const float* fc1_b   = (const float*)d_in[15];
  const float* fc2_w   = (const float*)d_in[16];
  const float* fc2_b   = (const float*)d_in[17];
  float* out = (float*)d_out;

  char* base = (char*)d_ws;
  size_t off = 0;
  auto alloc = [&](size_t bytes) -> void* {
    void* p = base + off;
    off = (off + bytes + 255) & ~(size_t)255;
    return p;
  };
  int*      lens     = (int*)     alloc(3 * NB * sizeof(int));
  float*    bias_sum = (float*)   alloc(NPAD * sizeof(float));
  _Float16* hcar     = (_Float16*)alloc((size_t)2*2*NB*KP * sizeof(_Float16));   // 655 KB
  float*    cst      = (float*)   alloc((size_t)2*NB*NH * sizeof(float));        // 614 KB
  _Float16* Wih16    = (_Float16*)alloc((size_t)NPAD*KP * sizeof(_Float16));     // 1.56 MB
  _Float16* Whh16    = (_Float16*)alloc((size_t)NPAD*KP * sizeof(_Float16));     // 1.56 MB
  float*    c_avg    = (float*)   alloc((size_t)NB*600 * sizeof(float));
  float*    a_avg    = (float*)   alloc((size_t)NB*600 * sizeof(float));
  float*    s1       = (float*)   alloc((size_t)NB*600 * sizeof(float));
  float*    s2       = (float*)   alloc((size_t)NB*600 * sizeof(float));
  float*    mca      = (float*)   alloc((size_t)NB*600 * sizeof(float));
  float*    mcc      = (float*)   alloc((size_t)NB*600 * sizeof(float));
  float*    mfa      = (float*)   alloc((size_t)NB*600 * sizeof(float));
  float*    mfc      = (float*)   alloc((size_t)NB*600 * sizeof(float));
  // hseqC region (39.3 MB) doubles as emb16 (20.5 MB) before the scans
  _Float16* hseqC    = (_Float16*)alloc((size_t)2*NS*NB*NH * sizeof(_Float16));
  _Float16* emb16    = hseqC;
  _Float16* hseqA    = (_Float16*)alloc((size_t)2*NA*NB*NH * sizeof(_Float16));  // 2.46 MB
  // BIG region: P (167 MB), overlaid later by ctx/ctxT/aspc (81 MB)
  char* bigBase = (char*)alloc((size_t)TOK_ALL * NPROJ * sizeof(_Float16));
  _Float16* P    = (_Float16*)bigBase;
  _Float16* ctx  = (_Float16*)bigBase;
  _Float16* ctxT = ctx  + (size_t)NB*NS*600;
  _Float16* aspc = ctxT + (size_t)NB*NS*600;
  if (ws_size < off) return;  // clean zero-output signal instead of OOB

  k_lengths<<<1, 256, 0, stream>>>(text, aspect, left, lens);
  k_cvt_emb<<<2048, 256, 0, stream>>>(emb, emb16);
  k_cvt_w<<<dim3(512, 3), 256, 0, stream>>>(Wih_f, Wih_b, Whh_f, Whh_b,
                                            bih_f, bhh_f, bih_b, bhh_b,
                                            Wih16, Whh16, bias_sum);
  k_inproj<<<dim3(272, 19), 256, 0, stream>>>(emb16, text, aspect, Wih16, bias_sum, P);

  hipMemsetAsync(hcar, 0, (size_t)2*2*NB*KP * sizeof(_Float16), stream);
  hipMemsetAsync(cst,  0, (size_t)2*NB*NH * sizeof(float), stream);
  for (int t = 0; t < NS; t++)
    k_lstm_step<<<dim3(19, 2, 4), 256, 0, stream>>>(P, Whh16, lens + NB,
                                                    hcar, cst, hseqC, t, NS, 0);
  hipMemsetAsync(hcar, 0, (size_t)2*2*NB*KP * sizeof(_Float16), stream);
  hipMemsetAsync(cst,  0, (size_t)2*NB*NH * sizeof(float), stream);
  for (int t = 0; t < NA; t++)
    k_lstm_step<<<dim3(19, 2, 4), 256, 0, stream>>>(P, Whh16, lens + 2*NB,
                                                    hcar, cst, hseqA, t, NA, TOK_CTX);

  k_combine_ctx<<<dim3(128, 16), 320, 0, stream>>>(hseqC, lens, ctx);
  k_transpose<<<dim3(256, 4, 19), 256, 0, stream>>>(ctx, ctxT);
  k_combine_asp<<<256, 320, 0, stream>>>(hseqA, lens, aspc);
  k_avg<<<256, 640, 0, stream>>>(ctx, aspc, lens, c_avg, a_avg);
  k_sw<<<dim3(32, 2), 640, 0, stream>>>(a_avg, c_avg, w1, w2, s1, s2);
  k_att_ctx<<<256, 128, 0, stream>>>(ctxT, ctx, s1, mca);
  k_att_asp<<<256, 512, 0, stream>>>(aspc, s2, mcc);
  k_u<<<256, 128, 0, stream>>>(ctxT, ctx, aspc, fc1_w, fc1_b, mfa, mfc);
  k_final<<<256, 192, 0, stream>>>(mca, mcc, mfa, mfc, fc2_w, fc2_b, out);
}